// Round 2
// baseline (174.332 us; speedup 1.0000x reference)
//
#include <hip/hip_runtime.h>
#include <hip/hip_bf16.h>

// RetinaNet focal classification loss, MI355X.
// Shapes: y_true (16,32,5) f32, y_classifs (16,200000,1) f32,
//         y_regressions (16,200000,4) f32 [UNUSED], anchors (200000,4) f32.
// Output: scalar FLOAT32 (reference returns f32; round-1 bf16 write read back ~0).
//
// ws layout (floats):
//   [0..15]   per-image loss sums   (atomic accum)
//   [16..31]  per-image pos counts  (atomic accum, exact in f32)
//   [32..]    gt table: 16*32 entries x 8 floats {x1,y1,x2,y2,area,label,pad,pad}

#define A_N 200000
#define B_N 16
#define G_N 32

// ---------------- kernel 1: zero accumulators + build gt table ----------------
__global__ void rnl_prep(const float* __restrict__ y_true, float* __restrict__ ws) {
    int i = threadIdx.x;
    if (i < 2 * B_N) ws[i] = 0.0f;           // zero loss sums + pos counts
    if (i < B_N * G_N) {
        float cx = y_true[i * 5 + 0];
        float cy = y_true[i * 5 + 1];
        float w  = y_true[i * 5 + 2];
        float h  = y_true[i * 5 + 3];
        float lb = y_true[i * 5 + 4];
        float x1 = cx - 0.5f * w, y1 = cy - 0.5f * h;
        float x2 = cx + 0.5f * w, y2 = cy + 0.5f * h;
        float area = (x2 - x1) * (y2 - y1);   // matches ref: from corners
        float* e = ws + 2 * B_N + i * 8;
        e[0] = x1; e[1] = y1; e[2] = x2; e[3] = y2;
        e[4] = area; e[5] = lb; e[6] = 0.f; e[7] = 0.f;
    }
}

// ---------------- kernel 2: main — one thread per (anchor, image) ----------------
__launch_bounds__(256)
__global__ void rnl_main(const float4* __restrict__ anchors,
                         const float* __restrict__ probs,
                         const float* __restrict__ gt,   // ws + 32
                         float* __restrict__ ws) {
    const int b = blockIdx.y;
    const int a = blockIdx.x * blockDim.x + threadIdx.x;

    float loss = 0.0f;
    float cnt  = 0.0f;

    if (a < A_N) {
        float4 an = anchors[a];                       // x1,y1,x2,y2
        float area_a = (an.z - an.x) * (an.w - an.y) + 1e-8f;  // fold ref's +1e-8

        const float* g = gt + b * G_N * 8;            // block-uniform -> s_load

        // running max of iou = inter/uni tracked as cross-product pair
        float bi = 0.0f, bu = 1.0f;
        float blab = g[5];                            // label of g=0 (argmax init 0)

        #pragma unroll
        for (int j = 0; j < G_N; ++j) {
            const float* e = g + j * 8;
            float gx1 = e[0], gy1 = e[1], gx2 = e[2], gy2 = e[3], ga = e[4];
            float ltx = fmaxf(an.x, gx1);
            float lty = fmaxf(an.y, gy1);
            float rbx = fminf(an.z, gx2);
            float rby = fminf(an.w, gy2);
            float iw  = fmaxf(rbx - ltx, 0.0f);
            float ih  = fmaxf(rby - lty, 0.0f);
            float inter = iw * ih;
            float uni   = (area_a + ga) - inter;       // > 0 always (eps folded)
            // inter/uni > bi/bu  <=>  inter*bu > bi*uni  (both denoms > 0)
            bool better = inter * bu > bi * uni;       // strict > keeps first max
            bi   = better ? inter : bi;
            bu   = better ? uni   : bu;
            blab = better ? e[5]  : blab;
        }

        float ioumax = bi / bu;
        float p = fminf(fmaxf(probs[b * A_N + a], 1e-7f), 1.0f - 1e-7f);

        if (ioumax >= 0.5f) {
            cnt = 1.0f;
            // target = one_hot(assigned, C=1) -> 1 iff label==0
            if (blab == 0.0f) {
                float q = 1.0f - p;
                loss = 0.25f * q * q * (-__logf(p));
            } else {
                loss = 0.75f * p * p * (-__logf(1.0f - p));
            }
        } else if (ioumax < 0.4f) {
            loss = 0.75f * p * p * (-__logf(1.0f - p));
        }
        // 0.4 <= iou < 0.5: ignored, loss stays 0
    }

    // block reduction: wave shuffle, then cross-wave via LDS, 2 atomics/block
    #pragma unroll
    for (int off = 32; off > 0; off >>= 1) {
        loss += __shfl_down(loss, off);
        cnt  += __shfl_down(cnt, off);
    }
    __shared__ float s_l[4], s_c[4];
    int wid  = threadIdx.x >> 6;
    int lane = threadIdx.x & 63;
    if (lane == 0) { s_l[wid] = loss; s_c[wid] = cnt; }
    __syncthreads();
    if (threadIdx.x == 0) {
        float L = s_l[0] + s_l[1] + s_l[2] + s_l[3];
        float C = s_c[0] + s_c[1] + s_c[2] + s_c[3];
        atomicAdd(&ws[b], L);
        atomicAdd(&ws[B_N + b], C);
    }
}

// ---------------- kernel 3: final mean over images ----------------
__global__ void rnl_final(const float* __restrict__ ws, float* __restrict__ out) {
    if (threadIdx.x == 0) {
        float s = 0.0f;
        #pragma unroll
        for (int b = 0; b < B_N; ++b) {
            s += ws[b] / fmaxf(ws[B_N + b], 1.0f);
        }
        out[0] = s * (1.0f / (float)B_N);
    }
}

extern "C" void kernel_launch(void* const* d_in, const int* in_sizes, int n_in,
                              void* d_out, int out_size, void* d_ws, size_t ws_size,
                              hipStream_t stream) {
    const float* y_true     = (const float*)d_in[0];
    const float* y_classifs = (const float*)d_in[1];
    // d_in[2] = y_regressions: unused by the loss
    const float* anchors    = (const float*)d_in[3];
    float* ws = (float*)d_ws;

    rnl_prep<<<1, 512, 0, stream>>>(y_true, ws);

    dim3 grid((A_N + 255) / 256, B_N);
    rnl_main<<<grid, 256, 0, stream>>>((const float4*)anchors, y_classifs,
                                       ws + 2 * B_N, ws);

    rnl_final<<<1, 64, 0, stream>>>(ws, (float*)d_out);
}

// Round 3
// 58.116 us; speedup vs baseline: 2.9997x; 2.9997x over previous
//
#include <hip/hip_runtime.h>
#include <hip/hip_bf16.h>

// RetinaNet focal classification loss, MI355X. Output: scalar f32.
//
// Round-3 structure: gt table staged in LDS (broadcast reads), 4 anchors per
// thread (amortize gt reads + ILP), uniform control flow (tail via clamp+mask)
// so no divergent-guard vmcnt serialization.
//
// ws layout (floats):
//   [0..15]   per-image loss sums   (atomic accum)
//   [16..31]  per-image pos counts  (atomic accum)
//   [32..]    gt table: 16*32 entries x 8 floats {x1,y1,x2,y2,area,label,pad,pad}

#define A_N 200000
#define B_N 16
#define G_N 32
#define APT 4                      // anchors per thread
#define BLK 256
#define TILE (BLK * APT)           // anchors per block = 1024

// ---------------- kernel 1: zero accumulators + build gt table ----------------
__global__ void rnl_prep(const float* __restrict__ y_true, float* __restrict__ ws) {
    int i = threadIdx.x;
    if (i < 2 * B_N) ws[i] = 0.0f;
    if (i < B_N * G_N) {
        float cx = y_true[i * 5 + 0];
        float cy = y_true[i * 5 + 1];
        float w  = y_true[i * 5 + 2];
        float h  = y_true[i * 5 + 3];
        float lb = y_true[i * 5 + 4];
        float x1 = cx - 0.5f * w, y1 = cy - 0.5f * h;
        float x2 = cx + 0.5f * w, y2 = cy + 0.5f * h;
        float area = (x2 - x1) * (y2 - y1);
        float* e = ws + 2 * B_N + i * 8;
        e[0] = x1; e[1] = y1; e[2] = x2; e[3] = y2;
        e[4] = area; e[5] = lb; e[6] = 0.f; e[7] = 0.f;
    }
}

// ---------------- kernel 2: main ----------------
__launch_bounds__(BLK)
__global__ void rnl_main(const float4* __restrict__ anchors,
                         const float* __restrict__ probs,
                         const float* __restrict__ gt,   // ws + 32
                         float* __restrict__ ws) {
    __shared__ float sgt[G_N * 8];          // 1 KB: this image's gt table

    const int b = blockIdx.y;
    const int t = threadIdx.x;
    const int base = blockIdx.x * TILE + t;

    // stage gt table (one float per thread, 256 of 256 threads)
    sgt[t] = gt[b * (G_N * 8) + t];
    __syncthreads();

    // per-anchor state, fully unrolled static indices -> registers
    float ax[APT], ay[APT], az[APT], aw[APT], sa[APT];
    float bi[APT], bu[APT], blab[APT], pv[APT], vmask[APT];

    const float lab0 = sgt[5];              // label of gt 0 (argmax init)

    #pragma unroll
    for (int k = 0; k < APT; ++k) {
        int idx  = base + k * BLK;
        int idxc = idx < A_N ? idx : A_N - 1;
        vmask[k] = idx < A_N ? 1.0f : 0.0f;
        float4 an = anchors[idxc];
        ax[k] = an.x; ay[k] = an.y; az[k] = an.z; aw[k] = an.w;
        sa[k] = (an.z - an.x) * (an.w - an.y) + 1e-8f;   // area_a + ref eps
        pv[k] = probs[b * A_N + idxc];
        bi[k] = 0.0f; bu[k] = 1.0f; blab[k] = lab0;
    }

    #pragma unroll
    for (int j = 0; j < G_N; ++j) {
        // uniform-address LDS reads: broadcast, conflict-free
        float4 gb = *reinterpret_cast<const float4*>(&sgt[j * 8]);      // x1,y1,x2,y2
        float2 ge = *reinterpret_cast<const float2*>(&sgt[j * 8 + 4]);  // area,label
        #pragma unroll
        for (int k = 0; k < APT; ++k) {
            float ltx = fmaxf(ax[k], gb.x);
            float lty = fmaxf(ay[k], gb.y);
            float rbx = fminf(az[k], gb.z);
            float rby = fminf(aw[k], gb.w);
            float iw  = fmaxf(rbx - ltx, 0.0f);
            float ih  = fmaxf(rby - lty, 0.0f);
            float inter = iw * ih;
            float uni   = (sa[k] + ge.x) - inter;        // > 0 (eps folded)
            // inter/uni > bi/bu  <=>  inter*bu > bi*uni (denoms > 0)
            bool better = inter * bu[k] > bi[k] * uni;
            bi[k]   = better ? inter : bi[k];
            bu[k]   = better ? uni   : bu[k];
            blab[k] = better ? ge.y  : blab[k];
        }
    }

    float loss = 0.0f, cnt = 0.0f;
    #pragma unroll
    for (int k = 0; k < APT; ++k) {
        float ioumax = bi[k] / bu[k];
        float p = fminf(fmaxf(pv[k], 1e-7f), 1.0f - 1e-7f);
        float q = 1.0f - p;
        bool  pos     = ioumax >= 0.5f;
        bool  takepos = pos && (blab[k] == 0.0f);        // one_hot hit (C=1)
        float x = takepos ? p : q;                       // single log argument
        float w = takepos ? 0.25f * q * q : 0.75f * p * p;
        float l = w * (-__logf(x));
        bool  active = pos || (ioumax < 0.4f);           // else ignore band
        l = active ? l : 0.0f;
        loss += vmask[k] * l;
        cnt  += pos ? vmask[k] : 0.0f;
    }

    // block reduction: wave shuffle, then cross-wave via LDS, 2 atomics/block
    #pragma unroll
    for (int off = 32; off > 0; off >>= 1) {
        loss += __shfl_down(loss, off);
        cnt  += __shfl_down(cnt, off);
    }
    __shared__ float s_l[4], s_c[4];
    int wid  = t >> 6;
    int lane = t & 63;
    if (lane == 0) { s_l[wid] = loss; s_c[wid] = cnt; }
    __syncthreads();
    if (t == 0) {
        float L = s_l[0] + s_l[1] + s_l[2] + s_l[3];
        float C = s_c[0] + s_c[1] + s_c[2] + s_c[3];
        atomicAdd(&ws[b], L);
        atomicAdd(&ws[B_N + b], C);
    }
}

// ---------------- kernel 3: final mean over images ----------------
__global__ void rnl_final(const float* __restrict__ ws, float* __restrict__ out) {
    if (threadIdx.x == 0) {
        float s = 0.0f;
        #pragma unroll
        for (int b = 0; b < B_N; ++b) {
            s += ws[b] / fmaxf(ws[B_N + b], 1.0f);
        }
        out[0] = s * (1.0f / (float)B_N);
    }
}

extern "C" void kernel_launch(void* const* d_in, const int* in_sizes, int n_in,
                              void* d_out, int out_size, void* d_ws, size_t ws_size,
                              hipStream_t stream) {
    const float* y_true     = (const float*)d_in[0];
    const float* y_classifs = (const float*)d_in[1];
    // d_in[2] = y_regressions: unused by the loss
    const float* anchors    = (const float*)d_in[3];
    float* ws = (float*)d_ws;

    rnl_prep<<<1, 512, 0, stream>>>(y_true, ws);

    dim3 grid((A_N + TILE - 1) / TILE, B_N);
    rnl_main<<<grid, BLK, 0, stream>>>((const float4*)anchors, y_classifs,
                                       ws + 2 * B_N, ws);

    rnl_final<<<1, 64, 0, stream>>>(ws, (float*)d_out);
}